// Round 10
// baseline (246.746 us; speedup 1.0000x reference)
//
#include <hip/hip_runtime.h>

#define GAMMA 0.999f
#define LAMBD 0.7f
#define ALPHA 0.99f

constexpr int A_DIM = 64;
constexpr int CH    = 128;   // rows per chunk; nch = T/CH = 2048
constexpr int BLK   = 256;   // 4 waves; each wave computes 32 rows of dots

typedef float fx4 __attribute__((ext_vector_type(4)));

__device__ __forceinline__ float dot4(const float4& a, const float4& b) {
    return a.x*b.x + a.y*b.y + a.z*b.z + a.w*b.w;
}
__device__ __forceinline__ void nt_store4(float* p, float x, float y, float z, float w) {
    fx4 v = { x, y, z, w };
    __builtin_nontemporal_store(v, (fx4*)p);
}
__device__ __forceinline__ unsigned long long pack2(float a, float b) {
    union { float f[2]; unsigned long long u; } x;
    x.f[0] = a; x.f[1] = b; return x.u;
}
__device__ __forceinline__ float2 unpack2(unsigned long long u) {
    union { unsigned long long u; float f[2]; } x;
    x.u = u; return make_float2(x.f[0], x.f[1]);
}

// ---------------------------------------------------------------------------
// Single kernel, decoupled lookback (reverse scan).
// Block b owns chunk c = nch-1-b (lookback walks to smaller block ids =
// earlier-dispatched => deadlock-free under FIFO dispatch).
//  A: action gathers + scalars.
//  B: software-pipelined dots (prefetch next iter's 8 float4s), 16-lane
//     butterflies -> v_t, v_tp1; NT float4 advantages write.
//  C: waves 0,1: affine suffix scan over the 128 rows; per-row {U,W} kept in
//     REGISTERS; tid0 publishes chunk aggregate (flag=1, release).
//  Lookback: wave 0, 64-wide windows: spin on flags, ordered prefix-compose
//     aggregates, stop at first inclusive; tid0 publishes inclusive (flag=2).
//  Finalize: targets[row] = U + W * ye.
// ---------------------------------------------------------------------------
__global__ __launch_bounds__(BLK, 8)
void k_main(const float* __restrict__ q, const float* __restrict__ q_tar,
            const float* __restrict__ pi, const int* __restrict__ a_t,
            const float* __restrict__ r_t, const float* __restrict__ mu_t,
            const int* __restrict__ done_t,
            float* __restrict__ adv_out, float* __restrict__ targets,
            unsigned long long* __restrict__ st_ab,
            unsigned long long* __restrict__ st_flag, int nch)
{
    __shared__ float sQa[CH], sPa[CH], sMa[CH], sKm[CH], sRt[CH];
    __shared__ float sV[CH], sVp[CH];
    __shared__ float sWA[2], sWB[2];
    __shared__ float sYe;

    const int tid  = threadIdx.x;
    const int wave = tid >> 6, lane = tid & 63;
    const int sub  = lane >> 4, li = lane & 15;
    const int bid  = blockIdx.x;
    const int R0   = (nch - 1 - bid) * CH;

    // ---- phase A: gathers + scalars
    if (tid < CH) {
        int r = R0 + tid;
        int a = a_t[r];
        sQa[tid] = q[r * A_DIM + a];
        sPa[tid] = pi[r * A_DIM + a];
    } else {
        int row = tid - CH;
        int r = R0 + row;
        int a = a_t[r];
        sMa[row] = mu_t[r * A_DIM + a];
        sRt[row] = r_t[r];
        sKm[row] = 1.0f - (float)done_t[r];
    }

    // ---- phase B: software-pipelined dots + advantages
    const int lrow0 = wave * 32 + sub;
    float4 piA, qA, pipA, qpA, piB, qB, pipB, qpB;
    {
        int gA = (R0 + lrow0) * A_DIM + li * 4;
        int gB = gA + 4 * A_DIM;
        piA  = *(const float4*)&pi[gA];
        qA   = *(const float4*)&q[gA];
        pipA = *(const float4*)&pi[gA + A_DIM];
        qpA  = *(const float4*)&q_tar[gA + A_DIM];
        piB  = *(const float4*)&pi[gB];
        qB   = *(const float4*)&q[gB];
        pipB = *(const float4*)&pi[gB + A_DIM];
        qpB  = *(const float4*)&q_tar[gB + A_DIM];
    }
    #pragma unroll
    for (int i = 0; i < 4; ++i) {
        float4 npiA, nqA, npipA, nqpA, npiB, nqB, npipB, nqpB;
        if (i < 3) {
            int gA = (R0 + lrow0 + (i + 1) * 8) * A_DIM + li * 4;
            int gB = gA + 4 * A_DIM;
            npiA  = *(const float4*)&pi[gA];
            nqA   = *(const float4*)&q[gA];
            npipA = *(const float4*)&pi[gA + A_DIM];
            nqpA  = *(const float4*)&q_tar[gA + A_DIM];
            npiB  = *(const float4*)&pi[gB];
            nqB   = *(const float4*)&q[gB];
            npipB = *(const float4*)&pi[gB + A_DIM];
            nqpB  = *(const float4*)&q_tar[gB + A_DIM];
        }

        int lrowA = lrow0 + i * 8;
        int lrowB = lrowA + 4;
        int gA = (R0 + lrowA) * A_DIM + li * 4;
        int gB = (R0 + lrowB) * A_DIM + li * 4;

        float s0A = dot4(piA, qA),  s1A = dot4(pipA, qpA);
        float s0B = dot4(piB, qB),  s1B = dot4(pipB, qpB);
        #pragma unroll
        for (int off = 1; off < 16; off <<= 1) {
            s0A += __shfl_xor(s0A, off);
            s1A += __shfl_xor(s1A, off);
            s0B += __shfl_xor(s0B, off);
            s1B += __shfl_xor(s1B, off);
        }

        nt_store4(&adv_out[gA],
                  (1.0f - ALPHA) * (qA.x - s0A), (1.0f - ALPHA) * (qA.y - s0A),
                  (1.0f - ALPHA) * (qA.z - s0A), (1.0f - ALPHA) * (qA.w - s0A));
        nt_store4(&adv_out[gB],
                  (1.0f - ALPHA) * (qB.x - s0B), (1.0f - ALPHA) * (qB.y - s0B),
                  (1.0f - ALPHA) * (qB.z - s0B), (1.0f - ALPHA) * (qB.w - s0B));

        if (li == 0) {
            sV[lrowA] = s0A;  sVp[lrowA] = s1A;
            sV[lrowB] = s0B;  sVp[lrowB] = s1B;
        }

        piA = npiA; qA = nqA; pipA = npipA; qpA = nqpA;
        piB = npiB; qB = nqB; pipB = npipB; qpB = nqpB;
    }
    __syncthreads();

    // ---- phase C: waves 0,1; lane owns row wave*64 + lane
    float Ai = 0.0f, Bi = 1.0f, Xa = 0.0f, Xb = 1.0f;
    float E = 0.0f, kmask = 0.0f;
    const int row = wave * 64 + lane;
    if (wave < 2) {
        float s0 = sV[row], s1 = sVp[row];
        kmask = sKm[row];
        float qa  = sQa[row];
        float rho = sPa[row] / sMa[row];
        float est = sRt[row] + kmask * (GAMMA * s1);
        float td  = est - qa;
        float c   = LAMBD * fminf(fmaxf(rho, 0.0f), 1.0f);
        float Fa  = (LAMBD * GAMMA) * rho * td;   // y_t = Fa + Fb*y_{t+1}
        float Fb  = kmask * (GAMMA * c);
        E = est + ALPHA * (qa - s0);              // targets = E + kmask*y_{t+1}

        Ai = Fa; Bi = Fb;                         // inclusive suffix scan
        #pragma unroll
        for (int off = 1; off < 64; off <<= 1) {
            float An = __shfl_down(Ai, off);
            float Bn = __shfl_down(Bi, off);
            if (lane + off < 64) { Ai += Bi * An; Bi *= Bn; }
        }
        if (lane == 0) { sWA[wave] = Ai; sWB[wave] = Bi; }
        Xa = __shfl_down(Ai, 1);                  // exclusive
        Xb = __shfl_down(Bi, 1);
        if (lane == 63) { Xa = 0.0f; Xb = 1.0f; }
    }
    __syncthreads();

    float U = 0.0f, W = 0.0f;
    float totA = 0.0f, totB = 1.0f;
    if (wave == 0) {
        // append wave 1's composite to wave 0's exclusive suffix
        Xa = Xa + Xb * sWA[1];
        Xb = Xb * sWB[1];
        totA = Ai + Bi * sWA[1];                  // full-chunk composite
        totB = Bi * sWB[1];
        if (lane == 0) {
            // publish AGGREGATE: ab (relaxed) then flag=1 (release)
            __hip_atomic_store(&st_ab[bid], pack2(totA, totB),
                               __ATOMIC_RELAXED, __HIP_MEMORY_SCOPE_AGENT);
            __hip_atomic_store(&st_flag[bid], 1ull,
                               __ATOMIC_RELEASE, __HIP_MEMORY_SCOPE_AGENT);
        }
    }
    if (wave < 2) {
        U = E + kmask * Xa;
        W = kmask * Xb;
    }

    // ---- lookback: wave 0, 64-wide windows toward block 0
    if (wave == 0) {
        float Aa = 0.0f, Bb = 1.0f;               // exclusive suffix (outer part)
        int base = bid - 1;
        bool done = (base < 0);
        while (!done) {
            int n = (base + 1 < 64) ? base + 1 : 64;
            int j = base - lane;                  // lane 0 = outermost
            unsigned long long f = 1;
            float2 v = make_float2(0.0f, 1.0f);   // identity pad
            if (lane < n) {
                do {
                    f = __hip_atomic_load(&st_flag[j], __ATOMIC_ACQUIRE,
                                          __HIP_MEMORY_SCOPE_AGENT);
                    if (f == 0) __builtin_amdgcn_s_sleep(1);
                } while (f == 0);
                v = unpack2(__hip_atomic_load(&st_ab[j], __ATOMIC_RELAXED,
                                              __HIP_MEMORY_SCOPE_AGENT));
            }
            unsigned long long bal = __ballot(lane < n && f == 2);
            int L = bal ? (__ffsll((long long)bal) - 1) : (n - 1);
            // ordered inclusive prefix (outer->inner) over lanes 0..63
            float Pa = v.x, Pb = v.y;
            #pragma unroll
            for (int off = 1; off < 64; off <<= 1) {
                float Uu = __shfl_up(Pa, off);
                float Vv = __shfl_up(Pb, off);
                if (lane >= off) { Pa = Uu + Vv * Pa; Pb = Vv * Pb; }
            }
            float Wa = __shfl(Pa, L);
            float Wb = __shfl(Pb, L);
            Aa = Aa + Bb * Wa;
            Bb = Bb * Wb;
            done = (bal != 0) || (base - L - 1 < 0);
            base -= (L + 1);
        }
        if (lane == 0) {
            // publish INCLUSIVE: own composite ∘ exclusive
            __hip_atomic_store(&st_ab[bid], pack2(totA + totB * Aa, totB * Bb),
                               __ATOMIC_RELAXED, __HIP_MEMORY_SCOPE_AGENT);
            __hip_atomic_store(&st_flag[bid], 2ull,
                               __ATOMIC_RELEASE, __HIP_MEMORY_SCOPE_AGENT);
            sYe = Aa;                             // y at end of this chunk
        }
    }
    __syncthreads();

    if (wave < 2) {
        float ye = sYe;
        __builtin_nontemporal_store(U + W * ye, &targets[R0 + row]);
    }
}

extern "C" void kernel_launch(void* const* d_in, const int* in_sizes, int n_in,
                              void* d_out, int out_size, void* d_ws, size_t ws_size,
                              hipStream_t stream) {
    const float* q      = (const float*)d_in[0];
    const float* q_tar  = (const float*)d_in[1];
    const float* pi     = (const float*)d_in[2];
    const int*   a_t    = (const int*)  d_in[3];
    const float* r_t    = (const float*)d_in[4];
    const float* mu_t   = (const float*)d_in[5];
    const int*   done_t = (const int*)  d_in[6];

    const int T   = in_sizes[3];         // 262144
    const int nch = T / CH;              // 2048

    float* targets = (float*)d_out;          // T floats
    float* adv     = (float*)d_out + T;      // T*A floats

    char* ws = (char*)d_ws;
    unsigned long long* st_ab   = (unsigned long long*)ws;
    unsigned long long* st_flag = (unsigned long long*)(ws + (size_t)8 * nch);

    hipMemsetAsync(st_flag, 0, (size_t)8 * nch, stream);
    k_main<<<nch, BLK, 0, stream>>>(q, q_tar, pi, a_t, r_t, mu_t, done_t,
                                    adv, targets, st_ab, st_flag, nch);
}

// Round 11
// 64.946 us; speedup vs baseline: 3.7993x; 3.7993x over previous
//
#include <hip/hip_runtime.h>

#define GAMMA 0.999f
#define LAMBD 0.7f
#define ALPHA 0.99f

constexpr int A_DIM = 64;
constexpr int CH    = 128;   // rows per block; nch = T/CH = 2048
constexpr int BLK   = 256;   // 4 waves; each wave computes 32 rows

typedef float fx4 __attribute__((ext_vector_type(4)));

__device__ __forceinline__ float dot4(const float4& a, const float4& b) {
    return a.x*b.x + a.y*b.y + a.z*b.z + a.w*b.w;
}
__device__ __forceinline__ void nt_store4(float* p, float x, float y, float z, float w) {
    fx4 v = { x, y, z, w };
    __builtin_nontemporal_store(v, (fx4*)p);
}

// ---------------------------------------------------------------------------
// K1: one 256-thread block per 128-row chunk.
//  Re-associated dots: d1[r] = pi[r]·q[r] (= v_t[r]), d2[r] = pi[r]·q_tar[r]
//  (v_tp1[r] = d2[r+1]) -> phase B loads only 3 SAME-ROW float4 streams
//  (pi, q, q_tar) instead of 4 (pi double-read eliminated).
//  A: action gathers + scalars; 16 spare lanes compute the boundary dot
//     d2[R0+128] (needs pi[R0+128]·q_tar[R0+128]).
//  B: software-pipelined (prefetch next iter's 6 float4s); 16-lane
//     butterflies for d1,d2; NT float4 advantages write.
//  C: waves 0,1 (lane owns row wave*64+lane): s1 = sVp[row+1]; affine
//     suffix scan via wave shuffles + cross-wave combine.
//     comb[t]={U,W}, cab[chunk]=composite.
// ---------------------------------------------------------------------------
__global__ __launch_bounds__(BLK, 4)
void k_main(const float* __restrict__ q, const float* __restrict__ q_tar,
            const float* __restrict__ pi, const int* __restrict__ a_t,
            const float* __restrict__ r_t, const float* __restrict__ mu_t,
            const int* __restrict__ done_t,
            float* __restrict__ adv_out,
            float2* __restrict__ comb, float2* __restrict__ cab)
{
    __shared__ float sQa[CH], sPa[CH], sMa[CH], sKm[CH], sRt[CH];
    __shared__ float sV[CH], sVp[CH + 1];
    __shared__ float sWA[2], sWB[2];

    const int tid  = threadIdx.x;
    const int wave = tid >> 6, lane = tid & 63;
    const int sub  = lane >> 4, li = lane & 15;
    const int R0   = blockIdx.x * CH;

    // ---- phase A: gathers + scalars (+ boundary dot d2[R0+CH])
    if (tid < CH) {
        int r = R0 + tid;
        int a = a_t[r];
        sQa[tid] = q[r * A_DIM + a];
        sPa[tid] = pi[r * A_DIM + a];
    } else {
        int row = tid - CH;
        int r = R0 + row;
        int a = a_t[r];
        sMa[row] = mu_t[r * A_DIM + a];
        sRt[row] = r_t[r];
        sKm[row] = 1.0f - (float)done_t[r];
    }
    if (tid >= 128 && tid < 144) {          // wave 2, lanes 0..15
        int l16  = tid - 128;
        int gE   = (R0 + CH) * A_DIM + l16 * 4;
        float4 pe = *(const float4*)&pi[gE];
        float4 qe = *(const float4*)&q_tar[gE];
        float d = dot4(pe, qe);
        #pragma unroll
        for (int off = 1; off < 16; off <<= 1) d += __shfl_xor(d, off);
        if (l16 == 0) sVp[CH] = d;
    }

    // ---- phase B: software-pipelined same-row dots + advantages
    const int lrow0 = wave * 32 + sub;
    float4 piA, qA, qtA, piB, qB, qtB;
    {
        int gA = (R0 + lrow0) * A_DIM + li * 4;
        int gB = gA + 4 * A_DIM;
        piA = *(const float4*)&pi[gA];
        qA  = *(const float4*)&q[gA];
        qtA = *(const float4*)&q_tar[gA];
        piB = *(const float4*)&pi[gB];
        qB  = *(const float4*)&q[gB];
        qtB = *(const float4*)&q_tar[gB];
    }
    #pragma unroll
    for (int i = 0; i < 4; ++i) {
        float4 npiA, nqA, nqtA, npiB, nqB, nqtB;
        if (i < 3) {
            int gA = (R0 + lrow0 + (i + 1) * 8) * A_DIM + li * 4;
            int gB = gA + 4 * A_DIM;
            npiA = *(const float4*)&pi[gA];
            nqA  = *(const float4*)&q[gA];
            nqtA = *(const float4*)&q_tar[gA];
            npiB = *(const float4*)&pi[gB];
            nqB  = *(const float4*)&q[gB];
            nqtB = *(const float4*)&q_tar[gB];
        }

        int lrowA = lrow0 + i * 8;
        int lrowB = lrowA + 4;
        int gA = (R0 + lrowA) * A_DIM + li * 4;
        int gB = (R0 + lrowB) * A_DIM + li * 4;

        float d1A = dot4(piA, qA),  d2A = dot4(piA, qtA);
        float d1B = dot4(piB, qB),  d2B = dot4(piB, qtB);
        #pragma unroll
        for (int off = 1; off < 16; off <<= 1) {
            d1A += __shfl_xor(d1A, off);
            d2A += __shfl_xor(d2A, off);
            d1B += __shfl_xor(d1B, off);
            d2B += __shfl_xor(d2B, off);
        }

        nt_store4(&adv_out[gA],
                  (1.0f - ALPHA) * (qA.x - d1A), (1.0f - ALPHA) * (qA.y - d1A),
                  (1.0f - ALPHA) * (qA.z - d1A), (1.0f - ALPHA) * (qA.w - d1A));
        nt_store4(&adv_out[gB],
                  (1.0f - ALPHA) * (qB.x - d1B), (1.0f - ALPHA) * (qB.y - d1B),
                  (1.0f - ALPHA) * (qB.z - d1B), (1.0f - ALPHA) * (qB.w - d1B));

        if (li == 0) {
            sV[lrowA]  = d1A;  sVp[lrowA] = d2A;
            sV[lrowB]  = d1B;  sVp[lrowB] = d2B;
        }

        piA = npiA; qA = nqA; qtA = nqtA;
        piB = npiB; qB = nqB; qtB = nqtB;
    }
    __syncthreads();

    // ---- phase C: waves 0,1; lane owns row wave*64 + lane
    float Ai = 0.0f, Bi = 1.0f, Xa = 0.0f, Xb = 1.0f;
    float E = 0.0f, kmask = 0.0f;
    const int row = wave * 64 + lane;
    if (wave < 2) {
        float s0 = sV[row];
        float s1 = sVp[row + 1];                  // v_tp1 = d2 of next row
        kmask = sKm[row];
        float qa  = sQa[row];
        float rho = sPa[row] / sMa[row];
        float est = sRt[row] + kmask * (GAMMA * s1);
        float td  = est - qa;
        float c   = LAMBD * fminf(fmaxf(rho, 0.0f), 1.0f);
        float Fa  = (LAMBD * GAMMA) * rho * td;   // y_t = Fa + Fb*y_{t+1}
        float Fb  = kmask * (GAMMA * c);
        E = est + ALPHA * (qa - s0);              // targets = E + kmask*y_{t+1}

        Ai = Fa; Bi = Fb;                         // inclusive suffix scan
        #pragma unroll
        for (int off = 1; off < 64; off <<= 1) {
            float An = __shfl_down(Ai, off);
            float Bn = __shfl_down(Bi, off);
            if (lane + off < 64) { Ai += Bi * An; Bi *= Bn; }
        }
        if (lane == 0) { sWA[wave] = Ai; sWB[wave] = Bi; }
        Xa = __shfl_down(Ai, 1);                  // exclusive
        Xb = __shfl_down(Bi, 1);
        if (lane == 63) { Xa = 0.0f; Xb = 1.0f; }
    }
    __syncthreads();
    if (wave < 2) {
        if (wave == 0) {                          // append wave 1's composite
            Xa = Xa + Xb * sWA[1];
            Xb = Xb * sWB[1];
        }
        comb[R0 + row] = make_float2(E + kmask * Xa, kmask * Xb);
        if (tid == 0)
            cab[blockIdx.x] = make_float2(Ai + Bi * sWA[1], Bi * sWB[1]);
    }
}

// ---------------------------------------------------------------------------
// K2: each 128-thread block finalizes one 128-row chunk. Redundant suffix
// scan of nch=2048 chunk composites (16 KB, L2-hot): 16-chunk register fold
// per thread -> 128 supers -> wave scan + cross-wave combine; thread 0 folds
// the <=16-entry tail to get ye for this chunk.
// ---------------------------------------------------------------------------
__global__ __launch_bounds__(BLK / 2, 8)
void k_fin(const float2* __restrict__ comb, const float2* __restrict__ cab,
           float* __restrict__ targets, int nch)
{
    __shared__ float sXa[128], sXb[128];
    __shared__ float sWA[2], sWB[2];
    __shared__ float sYe;
    const int tid = threadIdx.x, bid = blockIdx.x;
    const int wave = tid >> 6, lane = tid & 63;

    // fold 16 consecutive chunks (8 float4 loads), outer-first order
    const float4* cab4 = (const float4*)cab;
    float A = 0.0f, B = 1.0f;
    #pragma unroll
    for (int j = 0; j < 8; ++j) {
        float4 u = cab4[tid * 8 + j];
        A += B * u.x; B *= u.y;
        A += B * u.z; B *= u.w;
    }

    // suffix scan over 128 supers: wave shuffle + cross-wave combine
    float Ai = A, Bi = B;
    #pragma unroll
    for (int off = 1; off < 64; off <<= 1) {
        float An = __shfl_down(Ai, off);
        float Bn = __shfl_down(Bi, off);
        if (lane + off < 64) { Ai += Bi * An; Bi *= Bn; }
    }
    if (lane == 0) { sWA[wave] = Ai; sWB[wave] = Bi; }
    float Xa = __shfl_down(Ai, 1);
    float Xb = __shfl_down(Bi, 1);
    if (lane == 63) { Xa = 0.0f; Xb = 1.0f; }
    __syncthreads();
    if (wave == 0) {
        Xa = Xa + Xb * sWA[1];
        Xb = Xb * sWB[1];
    }
    sXa[tid] = Xa; sXb[tid] = Xb;   // exclusive suffix over supers > tid
    __syncthreads();

    if (tid == 0) {
        int c1 = bid + 1;                  // suffix over chunks c1..nch-1
        float ye;
        if (c1 >= nch) {
            ye = 0.0f;
        } else {
            int jq = c1 >> 4;
            float Aa = sXa[jq], Bb = sXb[jq];     // suffix over supers > jq
            for (int k2 = 16 * jq + 15; k2 >= c1; --k2) {
                float2 cv = cab[k2];
                Aa = cv.x + cv.y * Aa;
                Bb = cv.y * Bb;
            }
            ye = Aa;
        }
        sYe = ye;
    }
    __syncthreads();

    float2 uw = comb[bid * CH + tid];
    __builtin_nontemporal_store(uw.x + uw.y * sYe, &targets[bid * CH + tid]);
}

extern "C" void kernel_launch(void* const* d_in, const int* in_sizes, int n_in,
                              void* d_out, int out_size, void* d_ws, size_t ws_size,
                              hipStream_t stream) {
    const float* q      = (const float*)d_in[0];
    const float* q_tar  = (const float*)d_in[1];
    const float* pi     = (const float*)d_in[2];
    const int*   a_t    = (const int*)  d_in[3];
    const float* r_t    = (const float*)d_in[4];
    const float* mu_t   = (const float*)d_in[5];
    const int*   done_t = (const int*)  d_in[6];

    const int T   = in_sizes[3];         // 262144
    const int nch = T / CH;              // 2048

    float* targets = (float*)d_out;          // T floats
    float* adv     = (float*)d_out + T;      // T*A floats

    char* ws = (char*)d_ws;
    float2* comb = (float2*)ws;              ws += (size_t)8 * T;
    float2* cab  = (float2*)ws;

    k_main<<<nch, BLK, 0, stream>>>(q, q_tar, pi, a_t, r_t, mu_t, done_t,
                                    adv, comb, cab);
    k_fin<<<nch, BLK / 2, 0, stream>>>(comb, cab, targets, nch);
}

// Round 12
// 63.628 us; speedup vs baseline: 3.8779x; 1.0207x over previous
//
#include <hip/hip_runtime.h>

#define GAMMA 0.999f
#define LAMBD 0.7f
#define ALPHA 0.99f

constexpr int A_DIM = 64;
constexpr int CH    = 256;   // rows per block; nch = T/CH = 1024
constexpr int BLK   = 256;   // 4 waves; wave owns 64 rows

typedef float fx4 __attribute__((ext_vector_type(4)));

__device__ __forceinline__ float dot4(const float4& a, const float4& b) {
    return a.x*b.x + a.y*b.y + a.z*b.z + a.w*b.w;
}
__device__ __forceinline__ void nt_store4(float* p, float x, float y, float z, float w) {
    fx4 v = { x, y, z, w };
    __builtin_nontemporal_store(v, (fx4*)p);
}

// ---------------------------------------------------------------------------
// K1: one 256-thread block per 256-row chunk.
//  Decay insight: B_row <= lambda*gamma = 0.6993, so a 64-row suffix product
//  <= 1.1e-10 -> rows 0..191 of the chunk are numerically independent of the
//  next chunk: finalize them here (targets = U). Only rows 192..255 defer
//  their {U,W} to k_fin (targets = U + W*ye).
//  A: per-row gathers+scalars (1 row/thread) + boundary dot d2[R0+256].
//  B: software-pipelined same-row dots (pi,q,q_tar), 16-lane butterflies,
//     NT float4 advantages.
//  C: 4-wave segmented suffix scan (wave w scans rows [64w,64w+64)), segment
//     composites in LDS, scalar tail composite -> full exclusive suffix.
// ---------------------------------------------------------------------------
__global__ __launch_bounds__(BLK, 4)
void k_main(const float* __restrict__ q, const float* __restrict__ q_tar,
            const float* __restrict__ pi, const int* __restrict__ a_t,
            const float* __restrict__ r_t, const float* __restrict__ mu_t,
            const int* __restrict__ done_t,
            float* __restrict__ adv_out, float* __restrict__ targets,
            float2* __restrict__ combL, float2* __restrict__ cab)
{
    __shared__ float sQa[CH], sPa[CH], sMa[CH], sKm[CH], sRt[CH];
    __shared__ float sV[CH], sVp[CH + 1];
    __shared__ float sCA[4], sCB[4];

    const int tid  = threadIdx.x;
    const int wave = tid >> 6, lane = tid & 63;
    const int sub  = lane >> 4, li = lane & 15;
    const int R0   = blockIdx.x * CH;

    // ---- phase A: gathers + scalars (one row per thread)
    {
        int r = R0 + tid;
        int a = a_t[r];
        sQa[tid] = q[r * A_DIM + a];
        sPa[tid] = pi[r * A_DIM + a];
        sMa[tid] = mu_t[r * A_DIM + a];
        sRt[tid] = r_t[r];
        sKm[tid] = 1.0f - (float)done_t[r];
    }
    if (tid >= 192 && tid < 208) {          // boundary dot d2[R0+CH]
        int l16 = tid - 192;
        int gE  = (R0 + CH) * A_DIM + l16 * 4;
        float4 pe = *(const float4*)&pi[gE];
        float4 qe = *(const float4*)&q_tar[gE];
        float d = dot4(pe, qe);
        #pragma unroll
        for (int off = 1; off < 16; off <<= 1) d += __shfl_xor(d, off);
        if (l16 == 0) sVp[CH] = d;
    }

    // ---- phase B: software-pipelined same-row dots + advantages (8 iters)
    const int lrow0 = wave * 64 + sub;
    float4 piA, qA, qtA, piB, qB, qtB;
    {
        int gA = (R0 + lrow0) * A_DIM + li * 4;
        int gB = gA + 4 * A_DIM;
        piA = *(const float4*)&pi[gA];
        qA  = *(const float4*)&q[gA];
        qtA = *(const float4*)&q_tar[gA];
        piB = *(const float4*)&pi[gB];
        qB  = *(const float4*)&q[gB];
        qtB = *(const float4*)&q_tar[gB];
    }
    #pragma unroll
    for (int i = 0; i < 8; ++i) {
        float4 npiA, nqA, nqtA, npiB, nqB, nqtB;
        if (i < 7) {
            int gA = (R0 + lrow0 + (i + 1) * 8) * A_DIM + li * 4;
            int gB = gA + 4 * A_DIM;
            npiA = *(const float4*)&pi[gA];
            nqA  = *(const float4*)&q[gA];
            nqtA = *(const float4*)&q_tar[gA];
            npiB = *(const float4*)&pi[gB];
            nqB  = *(const float4*)&q[gB];
            nqtB = *(const float4*)&q_tar[gB];
        }

        int lrowA = lrow0 + i * 8;
        int lrowB = lrowA + 4;
        int gA = (R0 + lrowA) * A_DIM + li * 4;
        int gB = (R0 + lrowB) * A_DIM + li * 4;

        float d1A = dot4(piA, qA),  d2A = dot4(piA, qtA);
        float d1B = dot4(piB, qB),  d2B = dot4(piB, qtB);
        #pragma unroll
        for (int off = 1; off < 16; off <<= 1) {
            d1A += __shfl_xor(d1A, off);
            d2A += __shfl_xor(d2A, off);
            d1B += __shfl_xor(d1B, off);
            d2B += __shfl_xor(d2B, off);
        }

        nt_store4(&adv_out[gA],
                  (1.0f - ALPHA) * (qA.x - d1A), (1.0f - ALPHA) * (qA.y - d1A),
                  (1.0f - ALPHA) * (qA.z - d1A), (1.0f - ALPHA) * (qA.w - d1A));
        nt_store4(&adv_out[gB],
                  (1.0f - ALPHA) * (qB.x - d1B), (1.0f - ALPHA) * (qB.y - d1B),
                  (1.0f - ALPHA) * (qB.z - d1B), (1.0f - ALPHA) * (qB.w - d1B));

        if (li == 0) {
            sV[lrowA] = d1A;  sVp[lrowA] = d2A;
            sV[lrowB] = d1B;  sVp[lrowB] = d2B;
        }

        piA = npiA; qA = nqA; qtA = nqtA;
        piB = npiB; qB = nqB; qtB = nqtB;
    }
    __syncthreads();

    // ---- phase C: 4-wave segmented suffix scan; row == tid
    const int row = tid;
    float s0 = sV[row];
    float s1 = sVp[row + 1];                  // v_tp1 = d2 of next row
    float kmask = sKm[row];
    float qa  = sQa[row];
    float rho = sPa[row] / sMa[row];
    float est = sRt[row] + kmask * (GAMMA * s1);
    float td  = est - qa;
    float c   = LAMBD * fminf(fmaxf(rho, 0.0f), 1.0f);
    float Fa  = (LAMBD * GAMMA) * rho * td;   // y_t = Fa + Fb*y_{t+1}
    float Fb  = kmask * (GAMMA * c);
    float E   = est + ALPHA * (qa - s0);      // targets = E + kmask*y_{t+1}

    float Ai = Fa, Bi = Fb;                   // inclusive suffix scan (in-wave)
    #pragma unroll
    for (int off = 1; off < 64; off <<= 1) {
        float An = __shfl_down(Ai, off);
        float Bn = __shfl_down(Bi, off);
        if (lane + off < 64) { Ai += Bi * An; Bi *= Bn; }
    }
    if (lane == 0) { sCA[wave] = Ai; sCB[wave] = Bi; }
    float Xa = __shfl_down(Ai, 1);            // exclusive within segment
    float Xb = __shfl_down(Bi, 1);
    if (lane == 63) { Xa = 0.0f; Xb = 1.0f; }
    __syncthreads();

    // tail composite over segments wave+1..3 (outer->inner left fold)
    float Ta = 0.0f, Tb = 1.0f;
    for (int s = wave + 1; s < 4; ++s) {
        Ta += Tb * sCA[s];
        Tb *= sCB[s];
    }
    Xa = Xa + Xb * Ta;                        // full exclusive suffix in chunk
    Xb = Xb * Tb;

    float U = E + kmask * Xa;
    if (wave < 3) {
        // W = kmask*Xb <= 0.7^64 ~ 1e-10: next-chunk influence negligible
        __builtin_nontemporal_store(U, &targets[R0 + row]);
    } else {
        combL[blockIdx.x * 64 + lane] = make_float2(U, kmask * Xb);
    }
    if (tid == 0)                             // full chunk composite C0∘C1∘C2∘C3
        cab[blockIdx.x] = make_float2(Ai + Bi * Ta, Bi * Tb);
}

// ---------------------------------------------------------------------------
// K2: 64-lane block b finalizes rows 192..255 of chunk b. Redundant suffix
// scan of nch=1024 chunk composites (8 KB, L2-hot): 16-chunk fold per lane ->
// 64 supers -> wave suffix scan -> <=16-entry uniform tail fold -> ye.
// ---------------------------------------------------------------------------
__global__ __launch_bounds__(64, 8)
void k_fin(const float2* __restrict__ combL, const float2* __restrict__ cab,
           float* __restrict__ targets, int nch)
{
    const int lane = threadIdx.x, bid = blockIdx.x;

    const float4* cab4 = (const float4*)cab;
    float A = 0.0f, B = 1.0f;
    #pragma unroll
    for (int j = 0; j < 8; ++j) {             // fold 16 chunks (outer-first)
        float4 u = cab4[lane * 8 + j];
        A += B * u.x; B *= u.y;
        A += B * u.z; B *= u.w;
    }

    float Ai = A, Bi = B;                     // suffix scan over 64 supers
    #pragma unroll
    for (int off = 1; off < 64; off <<= 1) {
        float An = __shfl_down(Ai, off);
        float Bn = __shfl_down(Bi, off);
        if (lane + off < 64) { Ai += Bi * An; Bi *= Bn; }
    }
    float Xa = __shfl_down(Ai, 1);            // exclusive
    float Xb = __shfl_down(Bi, 1);
    if (lane == 63) { Xa = 0.0f; Xb = 1.0f; }

    float ye;
    int c1 = bid + 1;                         // need suffix over chunks c1..
    if (c1 >= nch) {
        ye = 0.0f;
    } else {
        int jq = c1 >> 4;
        float Aa = __shfl(Xa, jq);            // suffix over supers > jq
        float Bb = __shfl(Xb, jq);
        for (int k2 = 16 * jq + 15; k2 >= c1; --k2) {   // uniform, L2-broadcast
            float2 cv = cab[k2];
            Aa = cv.x + cv.y * Aa;
            Bb = cv.y * Bb;
        }
        ye = Aa;
    }

    float2 uw = combL[bid * 64 + lane];
    __builtin_nontemporal_store(uw.x + uw.y * ye,
                                &targets[bid * CH + 192 + lane]);
}

extern "C" void kernel_launch(void* const* d_in, const int* in_sizes, int n_in,
                              void* d_out, int out_size, void* d_ws, size_t ws_size,
                              hipStream_t stream) {
    const float* q      = (const float*)d_in[0];
    const float* q_tar  = (const float*)d_in[1];
    const float* pi     = (const float*)d_in[2];
    const int*   a_t    = (const int*)  d_in[3];
    const float* r_t    = (const float*)d_in[4];
    const float* mu_t   = (const float*)d_in[5];
    const int*   done_t = (const int*)  d_in[6];

    const int T   = in_sizes[3];         // 262144
    const int nch = T / CH;              // 1024

    float* targets = (float*)d_out;          // T floats
    float* adv     = (float*)d_out + T;      // T*A floats

    char* ws = (char*)d_ws;
    float2* combL = (float2*)ws;             ws += (size_t)8 * 64 * nch;
    float2* cab   = (float2*)ws;

    k_main<<<nch, BLK, 0, stream>>>(q, q_tar, pi, a_t, r_t, mu_t, done_t,
                                    adv, targets, combL, cab);
    k_fin<<<nch, 64, 0, stream>>>(combL, cab, targets, nch);
}